// Round 4
// baseline (952.783 us; speedup 1.0000x reference)
//
#include <hip/hip_runtime.h>

#define TT 100
#define DD 100
#define DC 25      // DD/4
#define PP 10
#define BBATCH 256
#define OC 80
#define KP 136     // kernel-B bf16 row stride (128 K-pad + 8 pad -> +4 banks/row)

typedef float v4f __attribute__((ext_vector_type(4)));
typedef float v4fa __attribute__((ext_vector_type(4)));
typedef short v8s __attribute__((ext_vector_type(8)));

static constexpr float FEPS = 1e-6f;
static constexpr float NEG_INF = -3.4e38f;

__device__ __forceinline__ float wsum(float v) {
#pragma unroll
  for (int m = 1; m < 64; m <<= 1) v += __shfl_xor(v, m, 64);
  return v;
}

__device__ __forceinline__ void wargmax(float& v, int& idx) {
#pragma unroll
  for (int m = 1; m < 64; m <<= 1) {
    float ov = __shfl_xor(v, m, 64);
    int   oi = __shfl_xor(idx, m, 64);
    if (ov > v || (ov == v && oi < idx)) { v = ov; idx = oi; }
  }
}

__device__ __forceinline__ unsigned short f2bf(float x) {  // RNE fp32->bf16
  union { float f; unsigned u; } v; v.f = x;
  unsigned r = v.u + 0x7FFF + ((v.u >> 16) & 1);
  return (unsigned short)(r >> 16);
}

// ---------------- Kernel A: everything except maxpool (fp32, argmax-exact) ---
__global__ __launch_bounds__(256, 2) void match_main(
    const float* __restrict__ s1, const float* __restrict__ s2,
    const float* __restrict__ w1, const float* __restrict__ w2,
    const float* __restrict__ w5, const float* __restrict__ w6,
    const float* __restrict__ w7, const float* __restrict__ w8,
    float* __restrict__ out)
{
  const int dir  = blockIdx.x & 1;
  const int b    = blockIdx.x >> 1;
  const int doff = dir * DD;
  const int tid  = threadIdx.x;
  const int lane = tid & 63;
  const int wv   = tid >> 6;

  const float* wfull = dir ? w2 : w1;
  const float* wmean = dir ? w6 : w5;
  const float* watt2 = dir ? w8 : w7;   // fwd: max-att (w7); bwd: mean-att (w8)

  __shared__ __align__(16) float S2V[DC][TT + 1][4];  // d-chunked s2, 40.4 KB
  __shared__ __align__(16) float S1R[16][DD];
  __shared__ __align__(16) float CROW[16][DD];
  __shared__ float N2PI[TT];
  __shared__ float N1PI[16];
  __shared__ int   ARGJ[16];

  // Phase 1: s2 tile
  for (int idx = tid; idx < TT * DD; idx += 256) {
    int j = idx / DD, d = idx - j * DD;
    S2V[d >> 2][j][d & 3] = s2[(j * BBATCH + b) * (2 * DD) + doff + d];
  }
  __syncthreads();

  // Phase 2: plain s2 norms (argmax-sensitive -> exact-ish sqrt+div)
  for (int task = tid; task < TT; task += 256) {
    float a = 0.f;
    for (int c = 0; c < DC; ++c) {
      v4f f = *(const v4f*)&S2V[c][task][0];
#pragma unroll
      for (int k = 0; k < 4; ++k) a = fmaf(f[k], f[k], a);
    }
    N2PI[task] = 1.0f / sqrtf(fmaxf(a, FEPS));
  }
  __syncthreads();

  const int  j0   = lane;
  const int  j1   = 64 + lane;
  const bool act1 = (j1 < TT);
  const int  j1c  = act1 ? j1 : (TT - 1);
  const bool actd = (64 + lane) < DD;
  const int  d1   = actd ? (64 + lane) : (DD - 1);
  const int  c0i  = lane >> 2, k0 = lane & 3;
  const int  c1i  = d1 >> 2,   k1 = d1 & 3;

  for (int t = 0; t < 7; ++t) {
    const int rbase = t * 16;
    for (int idx = tid; idx < 16 * DD; idx += 256) {
      int r = idx / DD, d = idx - r * DD;
      int row = rbase + r;
      S1R[r][d] = (row < TT) ? s1[(row * BBATCH + b) * (2 * DD) + doff + d] : 0.f;
    }
    __syncthreads();

    for (int task = tid; task < 16; task += 256) {
      float a = 0.f;
      for (int c = 0; c < DC; ++c) {
        v4f f = *(const v4f*)&S1R[task][4 * c];
#pragma unroll
        for (int k = 0; k < 4; ++k) a = fmaf(f[k], f[k], a);
      }
      N1PI[task] = 1.0f / sqrtf(fmaxf(a, FEPS));
    }
    __syncthreads();

    const int g = t * 4 + wv;
    const int i0 = g * 4;
    const int sl = wv * 4;
    const bool active = (g < 25);

    float rs[4] = {0, 0, 0, 0};
    float att0[4] = {0, 0, 0, 0}, att1[4] = {0, 0, 0, 0};

    // Phase B: plain dot only (scalar fma — maxpool moved to MFMA kernel)
    if (active) {
      float dot0[4] = {0, 0, 0, 0}, dot1[4] = {0, 0, 0, 0};
      for (int c = 0; c < DC; ++c) {
        v4f s2a4 = *(const v4f*)&S2V[c][j0][0];
        v4f s2b4 = *(const v4f*)&S2V[c][j1c][0];
        v4f s1v[4];
#pragma unroll
        for (int r = 0; r < 4; ++r) s1v[r] = *(const v4f*)&S1R[sl + r][4 * c];
#pragma unroll
        for (int k = 0; k < 4; ++k) {
#pragma unroll
          for (int r = 0; r < 4; ++r) {
            dot0[r] = fmaf(s1v[r][k], s2a4[k], dot0[r]);
            dot1[r] = fmaf(s1v[r][k], s2b4[k], dot1[r]);
          }
        }
      }

      // Phase C: cos rows, rowsum, argmax
#pragma unroll
      for (int r = 0; r < 4; ++r) {
        float n1pi_r = N1PI[sl + r];
        float c0 = dot0[r] * (n1pi_r * N2PI[j0]);
        float c1 = dot1[r] * (n1pi_r * N2PI[j1c]);
        CROW[sl + r][j0] = c0;
        if (act1) CROW[sl + r][j1] = c1;
        rs[r] = wsum(c0 + (act1 ? c1 : 0.f));

        float mv = c0; int mi = j0;
        if (act1 && (c1 > mv)) { mv = c1; mi = j1; }
        wargmax(mv, mi);
        if (lane == 0) ARGJ[sl + r] = mi;
      }
    }
    __syncthreads();

    // Phase D: mean-att accumulation; CROW read as b128 over 4-j chunks
    if (active) {
      for (int jb = 0; jb < TT; jb += 4) {
        v4f cr[4];
#pragma unroll
        for (int r = 0; r < 4; ++r) cr[r] = *(const v4f*)&CROW[sl + r][jb];
#pragma unroll
        for (int q = 0; q < 4; ++q) {
          int j = jb + q;
          float s2a = S2V[c0i][j][k0];
          float s2b = S2V[c1i][j][k1];
#pragma unroll
          for (int r = 0; r < 4; ++r) {
            att0[r] = fmaf(cr[r][q], s2a, att0[r]);
            att1[r] = fmaf(cr[r][q], s2b, att1[r]);
          }
        }
      }
    }
    __syncthreads();

    if (active) {
#pragma unroll
      for (int r = 0; r < 4; ++r) {
        float inv = 1.0f / (rs[r] + FEPS);
        CROW[sl + r][lane] = att0[r] * inv;
        if (actd) CROW[sl + r][64 + lane] = att1[r] * inv;
      }
    }
    __syncthreads();

    // Phase E: 120 tasks = 4 rows x {full, mean-att, att2} x 10 p
    if (active) {
      for (int tk = lane; tk < 120; tk += 64) {
        int r = tk / 30;
        int q = tk - r * 30;
        int set = q / PP;
        int p = q - set * PP;
        const float* wrow = (set == 0 ? wfull : (set == 1 ? wmean : watt2)) + p * DD;
        // reference quirk: s2.reshape(-1,D)[argmax] == s2f[0, argmax, :] (fwd only)
        const float* gat = s2 + ARGJ[sl + r] * (2 * DD);
        float num = 0.f, nx = 0.f, ny = 0.f;
        for (int c = 0; c < DC; ++c) {
          v4f x4 = *(const v4f*)&S1R[sl + r][4 * c];
          v4f y4;
          if (set == 0)                  y4 = *(const v4f*)&S2V[c][TT - 1][0];
          else if (set == 1 || dir == 1) y4 = *(const v4f*)&CROW[sl + r][4 * c];
          else                           y4 = *(const v4f*)&gat[4 * c];
          v4f w4 = *(const v4f*)&wrow[4 * c];
#pragma unroll
          for (int k = 0; k < 4; ++k) {
            float w2v = w4[k] * w4[k];
            num = fmaf(x4[k] * y4[k], w2v, num);
            nx  = fmaf(x4[k] * x4[k], w2v, nx);
            ny  = fmaf(y4[k] * y4[k], w2v, ny);
          }
        }
        float cres = num * rsqrtf(fmaxf(nx, FEPS)) * rsqrtf(fmaxf(ny, FEPS));
        int ch = (set == 0 ? 0 : (set == 1 ? 40 : 60)) + dir * PP + p;
        out[((i0 + r) * BBATCH + b) * OC + ch] = cres;
      }
    }
    __syncthreads();
  }
}

// ---------------- Kernel B: maxpool channels 20..39 via bf16 MFMA -----------
// C[i,j] = sum_d s1[i,d] * (s2[j,d]*w2[p,d]); cos = C * n1w[i,p] * n2w[j,p];
// out = max_j. num in bf16 (continuous max, ~2e-3 tail err), norms fp32.
__global__ __launch_bounds__(256, 2) void maxpool_mfma(
    const float* __restrict__ s1, const float* __restrict__ s2,
    const float* __restrict__ w3, const float* __restrict__ w4,
    float* __restrict__ out)
{
  const int dir  = blockIdx.x & 1;
  const int b    = blockIdx.x >> 1;
  const int doff = dir * DD;
  const float* wmax = dir ? w4 : w3;
  const int tid  = threadIdx.x;
  const int lane = tid & 63;
  const int wv   = tid >> 6;
  const int quad = lane >> 4;
  const int col  = lane & 15;

  __shared__ __align__(16) unsigned short Abf[TT][KP];  // s1 bf16, K-pad zeroed
  __shared__ __align__(16) unsigned short Bbf[TT][KP];  // s2*w^2 bf16, per p
  __shared__ float N1W[TT][PP];                         // fp32 1/norms
  __shared__ float N2Wp[112];

  // A build (once) + N1W
  for (int idx = tid; idx < TT * KP; idx += 256) {
    int i = idx / KP, q = idx - i * KP;
    float v = (q < DD) ? s1[(i * BBATCH + b) * (2 * DD) + doff + q] : 0.f;
    Abf[i][q] = f2bf(v);
  }
  for (int task = tid; task < TT * PP; task += 256) {
    int i = task / PP, p = task - i * PP;
    const float* s1r = s1 + (i * BBATCH + b) * (2 * DD) + doff;
    const float* wr  = wmax + p * DD;
    float a = 0.f;
    for (int c = 0; c < DC; ++c) {
      v4f x = *(const v4f*)&s1r[4 * c];
      v4f w = *(const v4f*)&wr[4 * c];
#pragma unroll
      for (int k = 0; k < 4; ++k) a = fmaf(x[k] * x[k], w[k] * w[k], a);
    }
    N1W[i][p] = rsqrtf(fmaxf(a, FEPS));
  }
  __syncthreads();

  for (int p = 0; p < PP; ++p) {
    const float* wr = wmax + p * DD;
    // B build for this p + n2w
    for (int idx = tid; idx < TT * KP; idx += 256) {
      int j = idx / KP, q = idx - j * KP;
      float v = 0.f;
      if (q < DD) { float w = wr[q]; v = s2[(j * BBATCH + b) * (2 * DD) + doff + q] * (w * w); }
      Bbf[j][q] = f2bf(v);
    }
    for (int task = tid; task < 112; task += 256) {
      float a = 0.f;
      if (task < TT) {
        const float* s2r = s2 + (task * BBATCH + b) * (2 * DD) + doff;
        for (int c = 0; c < DC; ++c) {
          v4f x = *(const v4f*)&s2r[4 * c];
          v4f w = *(const v4f*)&wr[4 * c];
#pragma unroll
          for (int k = 0; k < 4; ++k) a = fmaf(x[k] * x[k], w[k] * w[k], a);
        }
        N2Wp[task] = rsqrtf(fmaxf(a, FEPS));
      } else {
        N2Wp[task] = 0.f;
      }
    }
    __syncthreads();

    // MFMA: waves over i-tiles (7 of 16 rows); per tile loop 7 j-tiles x 4 K
    for (int it = wv; it < 7; it += 4) {
      int arow = min(it * 16 + col, TT - 1);   // clamp: dup rows, never written
      v8s afr[4];
#pragma unroll
      for (int kc = 0; kc < 4; ++kc)
        afr[kc] = *(const v8s*)&Abf[arow][kc * 32 + quad * 8];

      float rmax[4] = {NEG_INF, NEG_INF, NEG_INF, NEG_INF};
      for (int jt = 0; jt < 7; ++jt) {
        int brow = min(jt * 16 + col, TT - 1);
        v4fa acc = {0.f, 0.f, 0.f, 0.f};
#pragma unroll
        for (int kc = 0; kc < 4; ++kc) {
          v8s bfr = *(const v8s*)&Bbf[brow][kc * 32 + quad * 8];
          acc = __builtin_amdgcn_mfma_f32_16x16x32_bf16(afr[kc], bfr, acc, 0, 0, 0);
        }
        int jcol = jt * 16 + col;                 // C col = lane&15 [m89]
        if (jcol < TT) {
          float n2 = N2Wp[jcol];
#pragma unroll
          for (int r = 0; r < 4; ++r) rmax[r] = fmaxf(rmax[r], acc[r] * n2);
        }
      }
#pragma unroll
      for (int m = 1; m < 16; m <<= 1) {        // max over cols (quad preserved)
#pragma unroll
        for (int r = 0; r < 4; ++r) rmax[r] = fmaxf(rmax[r], __shfl_xor(rmax[r], m, 64));
      }
      if (col == 0) {
#pragma unroll
        for (int r = 0; r < 4; ++r) {
          int row = it * 16 + quad * 4 + r;      // C row = quad*4+reg [m89]
          if (row < TT)
            out[(row * BBATCH + b) * OC + 20 + dir * PP + p] = rmax[r] * N1W[row][p];
        }
      }
    }
    __syncthreads();  // before next-p Bbf overwrite
  }
}

extern "C" void kernel_launch(void* const* d_in, const int* in_sizes, int n_in,
                              void* d_out, int out_size, void* d_ws, size_t ws_size,
                              hipStream_t stream) {
  const float* s1 = (const float*)d_in[0];
  const float* s2 = (const float*)d_in[1];
  match_main<<<dim3(512), dim3(256), 0, stream>>>(
      s1, s2,
      (const float*)d_in[2], (const float*)d_in[3],   // w1, w2
      (const float*)d_in[6], (const float*)d_in[7],   // w5, w6
      (const float*)d_in[8], (const float*)d_in[9],   // w7, w8
      (float*)d_out);
  maxpool_mfma<<<dim3(512), dim3(256), 0, stream>>>(
      s1, s2,
      (const float*)d_in[4], (const float*)d_in[5],   // w3, w4
      (float*)d_out);
}

// Round 5
// 926.564 us; speedup vs baseline: 1.0283x; 1.0283x over previous
//
#include <hip/hip_runtime.h>
#include <hip/hip_bf16.h>

#define TT 100
#define DD 100
#define DC 25      // DD/4
#define PP 10
#define BBATCH 256
#define OC 80

typedef float v4f __attribute__((ext_vector_type(4)));
typedef short v8s __attribute__((ext_vector_type(8)));

static constexpr float FEPS = 1e-6f;
static constexpr float NEG_INF = -3.4e38f;

__device__ __forceinline__ float wsum(float v) {
#pragma unroll
  for (int m = 1; m < 64; m <<= 1) v += __shfl_xor(v, m, 64);
  return v;
}

__device__ __forceinline__ void wargmax(float& v, int& idx) {
#pragma unroll
  for (int m = 1; m < 64; m <<= 1) {
    float ov = __shfl_xor(v, m, 64);
    int   oi = __shfl_xor(idx, m, 64);
    if (ov > v || (ov == v && oi < idx)) { v = ov; idx = oi; }
  }
}

// RNE fp32 pair -> packed bf16x2 (lo in low 16 bits)
__device__ __forceinline__ unsigned pkbf(float lo, float hi) {
  __hip_bfloat162 h2 = __float22bfloat162_rn(make_float2(lo, hi));
  unsigned u; __builtin_memcpy(&u, &h2, sizeof(u));
  return u;
}

__global__ __launch_bounds__(256, 2) void match_fused(
    const float* __restrict__ s1, const float* __restrict__ s2,
    const float* __restrict__ w1, const float* __restrict__ w2,
    const float* __restrict__ w3, const float* __restrict__ w4,
    const float* __restrict__ w5, const float* __restrict__ w6,
    const float* __restrict__ w7, const float* __restrict__ w8,
    float* __restrict__ out)
{
  const int dir  = blockIdx.x & 1;
  const int b    = blockIdx.x >> 1;
  const int doff = dir * DD;
  const int tid  = threadIdx.x;
  const int lane = tid & 63;
  const int wv   = tid >> 6;

  const float* wfull = dir ? w2 : w1;
  const float* wmax  = dir ? w4 : w3;
  const float* wmean = dir ? w6 : w5;
  const float* watt2 = dir ? w8 : w7;   // fwd: max-att (w7); bwd: mean-att (w8)

  // s2 d-chunked: j-stride 16 B (b128 lane-over-j), chunk stride 404 dw (==20 mod 32)
  __shared__ __align__(16) float S2V[DC][TT + 1][4];  // 40.4 KB
  __shared__ __align__(16) float S1R[16][DD];         // 6.4 KB
  __shared__ __align__(16) float CROW[16][DD];        // 6.4 KB
  __shared__ float N2PI[TT];
  __shared__ float N1PI[16];
  __shared__ float N2W[TT][11];   // maxpool 1/norms of s2 (fp32), pad 11
  __shared__ float N1W[16][11];   // maxpool 1/norms of staged s1 rows
  __shared__ int   ARGJ[16];

  // ---- Phase 1: s2 tile ----
  for (int idx = tid; idx < TT * DD; idx += 256) {
    int j = idx / DD, d = idx - j * DD;
    S2V[d >> 2][j][d & 3] = s2[(j * BBATCH + b) * (2 * DD) + doff + d];
  }
  __syncthreads();

  // ---- Phase 2: s2 norms: plain (argmax-exact) + maxpool-weighted ----
  for (int task = tid; task < TT + TT * PP; task += 256) {
    if (task < TT) {
      float a = 0.f;
      for (int c = 0; c < DC; ++c) {
        v4f f = *(const v4f*)&S2V[c][task][0];
#pragma unroll
        for (int k = 0; k < 4; ++k) a = fmaf(f[k], f[k], a);
      }
      N2PI[task] = 1.0f / sqrtf(fmaxf(a, FEPS));
    } else {
      int q = task - TT; int j = q / PP, p = q - j * PP;
      const float* wr = wmax + p * DD;
      float a = 0.f;
      for (int c = 0; c < DC; ++c) {
        v4f f = *(const v4f*)&S2V[c][j][0];
        v4f w = *(const v4f*)&wr[4 * c];
#pragma unroll
        for (int k = 0; k < 4; ++k) a = fmaf(f[k] * f[k], w[k] * w[k], a);
      }
      N2W[j][p] = rsqrtf(fmaxf(a, FEPS));
    }
  }
  __syncthreads();

  const int  j0   = lane;
  const int  j1   = 64 + lane;
  const bool act1 = (j1 < TT);
  const int  j1c  = act1 ? j1 : (TT - 1);
  const bool actd = (64 + lane) < DD;
  const int  d1   = actd ? (64 + lane) : (DD - 1);
  const int  c0i  = lane >> 2, k0 = lane & 3;
  const int  c1i  = d1 >> 2,   k1 = d1 & 3;

  for (int t = 0; t < 7; ++t) {
    const int rbase = t * 16;
    for (int idx = tid; idx < 16 * DD; idx += 256) {
      int r = idx / DD, d = idx - r * DD;
      int row = rbase + r;
      S1R[r][d] = (row < TT) ? s1[(row * BBATCH + b) * (2 * DD) + doff + d] : 0.f;
    }
    __syncthreads();

    // s1 norms (plain + maxpool-weighted), cooperative
    for (int task = tid; task < 16 + 16 * PP; task += 256) {
      if (task < 16) {
        float a = 0.f;
        for (int c = 0; c < DC; ++c) {
          v4f f = *(const v4f*)&S1R[task][4 * c];
#pragma unroll
          for (int k = 0; k < 4; ++k) a = fmaf(f[k], f[k], a);
        }
        N1PI[task] = 1.0f / sqrtf(fmaxf(a, FEPS));
      } else {
        int q = task - 16; int rr = q / PP, p = q - rr * PP;
        const float* wr = wmax + p * DD;
        float a = 0.f;
        for (int c = 0; c < DC; ++c) {
          v4f f = *(const v4f*)&S1R[rr][4 * c];
          v4f w = *(const v4f*)&wr[4 * c];
#pragma unroll
          for (int k = 0; k < 4; ++k) a = fmaf(f[k] * f[k], w[k] * w[k], a);
        }
        N1W[rr][p] = rsqrtf(fmaxf(a, FEPS));
      }
    }
    __syncthreads();

    const int g = t * 4 + wv;
    const int i0 = g * 4;
    const int sl = wv * 4;
    const bool active = (g < 25);

    float rs[4] = {0, 0, 0, 0};
    float att0[4] = {0, 0, 0, 0}, att1[4] = {0, 0, 0, 0};

    // ---- Phase B+C: plain dot (fp32, argmax-exact), cos rows, rowsum, argmax
    if (active) {
      float dot0[4] = {0, 0, 0, 0}, dot1[4] = {0, 0, 0, 0};
      for (int c = 0; c < DC; ++c) {
        v4f s2a4 = *(const v4f*)&S2V[c][j0][0];
        v4f s2b4 = *(const v4f*)&S2V[c][j1c][0];
        v4f s1v[4];
#pragma unroll
        for (int r = 0; r < 4; ++r) s1v[r] = *(const v4f*)&S1R[sl + r][4 * c];
#pragma unroll
        for (int k = 0; k < 4; ++k) {
#pragma unroll
          for (int r = 0; r < 4; ++r) {
            dot0[r] = fmaf(s1v[r][k], s2a4[k], dot0[r]);
            dot1[r] = fmaf(s1v[r][k], s2b4[k], dot1[r]);
          }
        }
      }
#pragma unroll
      for (int r = 0; r < 4; ++r) {
        float n1pi_r = N1PI[sl + r];
        float c0 = dot0[r] * (n1pi_r * N2PI[j0]);
        float c1 = dot1[r] * (n1pi_r * N2PI[j1c]);
        CROW[sl + r][j0] = c0;
        if (act1) CROW[sl + r][j1] = c1;
        rs[r] = wsum(c0 + (act1 ? c1 : 0.f));

        float mv = c0; int mi = j0;
        if (act1 && (c1 > mv)) { mv = c1; mi = j1; }
        wargmax(mv, mi);
        if (lane == 0) ARGJ[sl + r] = mi;
      }
    }

    // ---- MFMA maxpool section (ALL waves; wave wv owns p in {wv, wv+4, wv+8})
    {
      const int col = lane & 15;
      const int qd  = lane >> 4;
      const int np  = (wv < 2) ? 3 : 2;
      union FragU { v8s v; unsigned u[4]; };
      const v4f vz = {0.f, 0.f, 0.f, 0.f};

      // A_p = bf16(s1 * w^2_p), row = col (staged local rows), cached per p
      v8s afr[3][4];
      for (int pi = 0; pi < np; ++pi) {
        int p = wv + 4 * pi;
        const float* wr = wmax + p * DD;
#pragma unroll
        for (int kc = 0; kc < 4; ++kc) {
          int d0 = kc * 32 + qd * 8;
          v4f x0, x1, w0, w1;
          if (kc < 3) {
            x0 = *(const v4f*)&S1R[col][d0];
            x1 = *(const v4f*)&S1R[col][d0 + 4];
            w0 = *(const v4f*)&wr[d0];
            w1 = *(const v4f*)&wr[d0 + 4];
          } else {                 // d0 = 96+8*qd: only qd==0 first half valid
            bool ok = (qd == 0);
            x0 = ok ? *(const v4f*)&S1R[col][96] : vz;
            w0 = ok ? *(const v4f*)&wr[96] : vz;
            x1 = vz; w1 = vz;
          }
          float pr[8];
#pragma unroll
          for (int k = 0; k < 4; ++k) {
            pr[k]     = x0[k] * (w0[k] * w0[k]);
            pr[4 + k] = x1[k] * (w1[k] * w1[k]);
          }
          FragU f;
#pragma unroll
          for (int e = 0; e < 4; ++e) f.u[e] = pkbf(pr[2 * e], pr[2 * e + 1]);
          afr[pi][kc] = f.v;
        }
      }

      float rmax[3][4];
#pragma unroll
      for (int pi = 0; pi < 3; ++pi)
#pragma unroll
        for (int r = 0; r < 4; ++r) rmax[pi][r] = NEG_INF;

      for (int jt = 0; jt < 7; ++jt) {
        int jr = jt * 16 + col;
        int jc = (jr < TT) ? jr : (TT - 1);
        v8s bfr[4];                       // B = bf16(s2), row = jr
#pragma unroll
        for (int kc = 0; kc < 4; ++kc) {
          int ch = kc * 8 + qd * 2;
          v4f y0 = *(const v4f*)&S2V[(ch <= 24) ? ch : 24][jc][0];
          if (ch > 24) y0 = vz;
          int ch1 = ch + 1;
          v4f y1 = *(const v4f*)&S2V[(ch1 <= 24) ? ch1 : 24][jc][0];
          if (ch1 > 24) y1 = vz;
          FragU f;
          f.u[0] = pkbf(y0[0], y0[1]); f.u[1] = pkbf(y0[2], y0[3]);
          f.u[2] = pkbf(y1[0], y1[1]); f.u[3] = pkbf(y1[2], y1[3]);
          bfr[kc] = f.v;
        }
        for (int pi = 0; pi < np; ++pi) {
          int p = wv + 4 * pi;
          v4f acc = {0.f, 0.f, 0.f, 0.f};
#pragma unroll
          for (int kc = 0; kc < 4; ++kc)
            acc = __builtin_amdgcn_mfma_f32_16x16x32_bf16(afr[pi][kc], bfr[kc], acc, 0, 0, 0);
          if (jr < TT) {                 // C col = lane&15 -> j (m89/R4-verified)
            float n2 = N2W[jr][p];
#pragma unroll
            for (int r = 0; r < 4; ++r)
              rmax[pi][r] = fmaxf(rmax[pi][r], acc[r] * n2);
          }
        }
      }
      for (int pi = 0; pi < np; ++pi) {
        int p = wv + 4 * pi;
#pragma unroll
        for (int m = 1; m < 16; m <<= 1)
#pragma unroll
          for (int r = 0; r < 4; ++r)
            rmax[pi][r] = fmaxf(rmax[pi][r], __shfl_xor(rmax[pi][r], m, 64));
        if (col == 0) {
#pragma unroll
          for (int r = 0; r < 4; ++r) {
            int lrow = qd * 4 + r;       // C row = quad*4+reg (m89/R4-verified)
            int row = rbase + lrow;
            if (row < TT)
              out[(row * BBATCH + b) * OC + 20 + dir * PP + p] =
                  rmax[pi][r] * N1W[lrow][p];
          }
        }
      }
    }
    __syncthreads();  // CROW + ARGJ visible block-wide

    // ---- Phase D: mean-att accumulation ----
    if (active) {
      for (int jb = 0; jb < TT; jb += 4) {
        v4f cr[4];
#pragma unroll
        for (int r = 0; r < 4; ++r) cr[r] = *(const v4f*)&CROW[sl + r][jb];
#pragma unroll
        for (int q = 0; q < 4; ++q) {
          int j = jb + q;
          float s2a = S2V[c0i][j][k0];
          float s2b = S2V[c1i][j][k1];
#pragma unroll
          for (int r = 0; r < 4; ++r) {
            att0[r] = fmaf(cr[r][q], s2a, att0[r]);
            att1[r] = fmaf(cr[r][q], s2b, att1[r]);
          }
        }
      }
    }
    __syncthreads();

    if (active) {
#pragma unroll
      for (int r = 0; r < 4; ++r) {
        float inv = 1.0f / (rs[r] + FEPS);
        CROW[sl + r][lane] = att0[r] * inv;
        if (actd) CROW[sl + r][64 + lane] = att1[r] * inv;
      }
    }
    __syncthreads();

    // ---- Phase E: 120 tasks = 4 rows x {full, mean-att, att2} x 10 p ----
    if (active) {
      for (int tk = lane; tk < 120; tk += 64) {
        int r = tk / 30;
        int q = tk - r * 30;
        int set = q / PP;
        int p = q - set * PP;
        const float* wrow = (set == 0 ? wfull : (set == 1 ? wmean : watt2)) + p * DD;
        // reference quirk: s2.reshape(-1,D)[argmax] == s2f[0, argmax, :] (fwd only)
        const float* gat = s2 + ARGJ[sl + r] * (2 * DD);
        float num = 0.f, nx = 0.f, ny = 0.f;
        for (int c = 0; c < DC; ++c) {
          v4f x4 = *(const v4f*)&S1R[sl + r][4 * c];
          v4f y4;
          if (set == 0)                  y4 = *(const v4f*)&S2V[c][TT - 1][0];
          else if (set == 1 || dir == 1) y4 = *(const v4f*)&CROW[sl + r][4 * c];
          else                           y4 = *(const v4f*)&gat[4 * c];
          v4f w4 = *(const v4f*)&wrow[4 * c];
#pragma unroll
          for (int k = 0; k < 4; ++k) {
            float w2v = w4[k] * w4[k];
            num = fmaf(x4[k] * y4[k], w2v, num);
            nx  = fmaf(x4[k] * x4[k], w2v, nx);
            ny  = fmaf(y4[k] * y4[k], w2v, ny);
          }
        }
        float cres = num * rsqrtf(fmaxf(nx, FEPS)) * rsqrtf(fmaxf(ny, FEPS));
        int ch = (set == 0 ? 0 : (set == 1 ? 40 : 60)) + dir * PP + p;
        out[((i0 + r) * BBATCH + b) * OC + ch] = cres;
      }
    }
    __syncthreads();
  }
}

extern "C" void kernel_launch(void* const* d_in, const int* in_sizes, int n_in,
                              void* d_out, int out_size, void* d_ws, size_t ws_size,
                              hipStream_t stream) {
  const float* s1 = (const float*)d_in[0];
  const float* s2 = (const float*)d_in[1];
  match_fused<<<dim3(512), dim3(256), 0, stream>>>(
      s1, s2,
      (const float*)d_in[2], (const float*)d_in[3],
      (const float*)d_in[4], (const float*)d_in[5],
      (const float*)d_in[6], (const float*)d_in[7],
      (const float*)d_in[8], (const float*)d_in[9],
      (float*)d_out);
}

// Round 6
// 853.626 us; speedup vs baseline: 1.1162x; 1.0854x over previous
//
#include <hip/hip_runtime.h>
#include <hip/hip_bf16.h>

#define TT 100
#define DD 100
#define DC 25      // DD/4
#define PP 10
#define BBATCH 256
#define OC 80

typedef float v4f __attribute__((ext_vector_type(4)));
typedef short v8s __attribute__((ext_vector_type(8)));

static constexpr float FEPS = 1e-6f;
static constexpr float NEG_INF = -3.4e38f;

__device__ __forceinline__ float wsum(float v) {
#pragma unroll
  for (int m = 1; m < 64; m <<= 1) v += __shfl_xor(v, m, 64);
  return v;
}

__device__ __forceinline__ void wargmax(float& v, int& idx) {
#pragma unroll
  for (int m = 1; m < 64; m <<= 1) {
    float ov = __shfl_xor(v, m, 64);
    int   oi = __shfl_xor(idx, m, 64);
    if (ov > v || (ov == v && oi < idx)) { v = ov; idx = oi; }
  }
}

// RNE fp32 pair -> packed bf16x2 (lo in low 16 bits)
__device__ __forceinline__ unsigned pkbf(float lo, float hi) {
  __hip_bfloat162 h2 = __float22bfloat162_rn(make_float2(lo, hi));
  unsigned u; __builtin_memcpy(&u, &h2, sizeof(u));
  return u;
}

__global__ __launch_bounds__(256, 2) void match_fused(
    const float* __restrict__ s1, const float* __restrict__ s2,
    const float* __restrict__ w1, const float* __restrict__ w2,
    const float* __restrict__ w3, const float* __restrict__ w4,
    const float* __restrict__ w5, const float* __restrict__ w6,
    const float* __restrict__ w7, const float* __restrict__ w8,
    float* __restrict__ out)
{
  const int dir  = blockIdx.x & 1;
  const int b    = blockIdx.x >> 1;
  const int doff = dir * DD;
  const int tid  = threadIdx.x;
  const int lane = tid & 63;
  const int wv   = tid >> 6;

  const float* wfull = dir ? w2 : w1;
  const float* wmax  = dir ? w4 : w3;
  const float* wmean = dir ? w6 : w5;
  const float* watt2 = dir ? w8 : w7;   // fwd: max-att (w7); bwd: mean-att (w8)

  // s2 d-chunked: j-stride 16 B (b128 lane-over-j), chunk stride 404 dw (==20 mod 32)
  __shared__ __align__(16) float S2V[DC][TT + 1][4];  // 40.4 KB
  __shared__ __align__(16) float S1R[16][DD];         // 6.4 KB
  __shared__ __align__(16) float CROW[16][DD];        // 6.4 KB
  __shared__ float N2PI[TT];
  __shared__ float N1PI[16];
  __shared__ float N2W[TT][11];   // maxpool 1/norms of s2 (fp32), pad 11
  __shared__ float N1W[16][11];   // maxpool 1/norms of staged s1 rows
  __shared__ int   ARGJ[16];

  // ---- Phase 1: s2 tile ----
  for (int idx = tid; idx < TT * DD; idx += 256) {
    int j = idx / DD, d = idx - j * DD;
    S2V[d >> 2][j][d & 3] = s2[(j * BBATCH + b) * (2 * DD) + doff + d];
  }
  __syncthreads();

  // ---- Phase 2: s2 norms: plain (argmax-exact) + maxpool-weighted ----
  for (int task = tid; task < TT + TT * PP; task += 256) {
    if (task < TT) {
      float a = 0.f;
      for (int c = 0; c < DC; ++c) {
        v4f f = *(const v4f*)&S2V[c][task][0];
#pragma unroll
        for (int k = 0; k < 4; ++k) a = fmaf(f[k], f[k], a);
      }
      N2PI[task] = 1.0f / sqrtf(fmaxf(a, FEPS));
    } else {
      int q = task - TT; int j = q / PP, p = q - j * PP;
      const float* wr = wmax + p * DD;
      float a = 0.f;
      for (int c = 0; c < DC; ++c) {
        v4f f = *(const v4f*)&S2V[c][j][0];
        v4f w = *(const v4f*)&wr[4 * c];
#pragma unroll
        for (int k = 0; k < 4; ++k) a = fmaf(f[k] * f[k], w[k] * w[k], a);
      }
      N2W[j][p] = rsqrtf(fmaxf(a, FEPS));
    }
  }
  __syncthreads();

  const int  j0   = lane;
  const int  j1   = 64 + lane;
  const bool act1 = (j1 < TT);
  const int  j1c  = act1 ? j1 : (TT - 1);
  const bool actd = (64 + lane) < DD;
  const int  d1   = actd ? (64 + lane) : (DD - 1);
  const int  c0i  = lane >> 2, k0 = lane & 3;
  const int  c1i  = d1 >> 2,   k1 = d1 & 3;

  for (int t = 0; t < 7; ++t) {
    const int rbase = t * 16;
    for (int idx = tid; idx < 16 * DD; idx += 256) {
      int r = idx / DD, d = idx - r * DD;
      int row = rbase + r;
      S1R[r][d] = (row < TT) ? s1[(row * BBATCH + b) * (2 * DD) + doff + d] : 0.f;
    }
    __syncthreads();

    // s1 norms (plain + maxpool-weighted), cooperative
    for (int task = tid; task < 16 + 16 * PP; task += 256) {
      if (task < 16) {
        float a = 0.f;
        for (int c = 0; c < DC; ++c) {
          v4f f = *(const v4f*)&S1R[task][4 * c];
#pragma unroll
          for (int k = 0; k < 4; ++k) a = fmaf(f[k], f[k], a);
        }
        N1PI[task] = 1.0f / sqrtf(fmaxf(a, FEPS));
      } else {
        int q = task - 16; int rr = q / PP, p = q - rr * PP;
        const float* wr = wmax + p * DD;
        float a = 0.f;
        for (int c = 0; c < DC; ++c) {
          v4f f = *(const v4f*)&S1R[rr][4 * c];
          v4f w = *(const v4f*)&wr[4 * c];
#pragma unroll
          for (int k = 0; k < 4; ++k) a = fmaf(f[k] * f[k], w[k] * w[k], a);
        }
        N1W[rr][p] = rsqrtf(fmaxf(a, FEPS));
      }
    }
    __syncthreads();

    const int g = t * 4 + wv;
    const int i0 = g * 4;
    const int sl = wv * 4;
    const bool active = (g < 25);

    float rs[4] = {0, 0, 0, 0};
    float att0[4] = {0, 0, 0, 0}, att1[4] = {0, 0, 0, 0};

    // ---- Phase B+C: plain dot (fp32, argmax-exact), cos rows, rowsum, argmax
    if (active) {
      float dot0[4] = {0, 0, 0, 0}, dot1[4] = {0, 0, 0, 0};
      for (int c = 0; c < DC; ++c) {
        v4f s2a4 = *(const v4f*)&S2V[c][j0][0];
        v4f s2b4 = *(const v4f*)&S2V[c][j1c][0];
        v4f s1v[4];
#pragma unroll
        for (int r = 0; r < 4; ++r) s1v[r] = *(const v4f*)&S1R[sl + r][4 * c];
#pragma unroll
        for (int k = 0; k < 4; ++k) {
#pragma unroll
          for (int r = 0; r < 4; ++r) {
            dot0[r] = fmaf(s1v[r][k], s2a4[k], dot0[r]);
            dot1[r] = fmaf(s1v[r][k], s2b4[k], dot1[r]);
          }
        }
      }
#pragma unroll
      for (int r = 0; r < 4; ++r) {
        float n1pi_r = N1PI[sl + r];
        float c0 = dot0[r] * (n1pi_r * N2PI[j0]);
        float c1 = dot1[r] * (n1pi_r * N2PI[j1c]);
        CROW[sl + r][j0] = c0;
        if (act1) CROW[sl + r][j1] = c1;
        rs[r] = wsum(c0 + (act1 ? c1 : 0.f));

        float mv = c0; int mi = j0;
        if (act1 && (c1 > mv)) { mv = c1; mi = j1; }
        wargmax(mv, mi);
        if (lane == 0) ARGJ[sl + r] = mi;
      }
    }

    // ---- MFMA maxpool section. COMPILE-TIME pi unroll (3): dynamic-trip loop
    // over register arrays demoted afr/rmax to scratch in R5 -> 1.8 GB HBM.
    // Waves 2,3 duplicate their last p (clamped); store is validity-guarded.
    {
      const int col = lane & 15;
      const int qd  = lane >> 4;
      union FragU { v8s v; unsigned u[4]; };
      const v4f vz = {0.f, 0.f, 0.f, 0.f};

      v8s afr[3][4];
      float rmax[3][4];
#pragma unroll
      for (int pi = 0; pi < 3; ++pi) {
        const int p = (wv + 4 * pi < PP) ? (wv + 4 * pi) : (PP - 1);
        const float* wr = wmax + p * DD;
#pragma unroll
        for (int kc = 0; kc < 4; ++kc) {
          int d0 = kc * 32 + qd * 8;
          v4f x0, x1, w0, w1;
          if (kc < 3) {
            x0 = *(const v4f*)&S1R[col][d0];
            x1 = *(const v4f*)&S1R[col][d0 + 4];
            w0 = *(const v4f*)&wr[d0];
            w1 = *(const v4f*)&wr[d0 + 4];
          } else {                 // d0 = 96+8*qd: only qd==0 first half valid
            bool ok = (qd == 0);
            x0 = ok ? *(const v4f*)&S1R[col][96] : vz;
            w0 = ok ? *(const v4f*)&wr[96] : vz;
            x1 = vz; w1 = vz;
          }
          float pr[8];
#pragma unroll
          for (int k = 0; k < 4; ++k) {
            pr[k]     = x0[k] * (w0[k] * w0[k]);
            pr[4 + k] = x1[k] * (w1[k] * w1[k]);
          }
          FragU f;
#pragma unroll
          for (int e = 0; e < 4; ++e) f.u[e] = pkbf(pr[2 * e], pr[2 * e + 1]);
          afr[pi][kc] = f.v;
        }
#pragma unroll
        for (int r = 0; r < 4; ++r) rmax[pi][r] = NEG_INF;
      }

      for (int jt = 0; jt < 7; ++jt) {
        int jr = jt * 16 + col;
        int jc = (jr < TT) ? jr : (TT - 1);
        v8s bfr[4];                       // B = bf16(s2), row = jr
#pragma unroll
        for (int kc = 0; kc < 4; ++kc) {
          int ch = kc * 8 + qd * 2;
          v4f y0 = *(const v4f*)&S2V[(ch <= 24) ? ch : 24][jc][0];
          if (ch > 24) y0 = vz;
          int ch1 = ch + 1;
          v4f y1 = *(const v4f*)&S2V[(ch1 <= 24) ? ch1 : 24][jc][0];
          if (ch1 > 24) y1 = vz;
          FragU f;
          f.u[0] = pkbf(y0[0], y0[1]); f.u[1] = pkbf(y0[2], y0[3]);
          f.u[2] = pkbf(y1[0], y1[1]); f.u[3] = pkbf(y1[2], y1[3]);
          bfr[kc] = f.v;
        }
#pragma unroll
        for (int pi = 0; pi < 3; ++pi) {
          const int p = (wv + 4 * pi < PP) ? (wv + 4 * pi) : (PP - 1);
          v4f acc = {0.f, 0.f, 0.f, 0.f};
#pragma unroll
          for (int kc = 0; kc < 4; ++kc)
            acc = __builtin_amdgcn_mfma_f32_16x16x32_bf16(afr[pi][kc], bfr[kc], acc, 0, 0, 0);
          if (jr < TT) {                 // C col = lane&15 -> j (m89/R4-verified)
            float n2 = N2W[jr][p];
#pragma unroll
            for (int r = 0; r < 4; ++r)
              rmax[pi][r] = fmaxf(rmax[pi][r], acc[r] * n2);
          }
        }
      }
#pragma unroll
      for (int pi = 0; pi < 3; ++pi) {
        const int p = wv + 4 * pi;
        if (p < PP) {                    // wave-uniform guard
#pragma unroll
          for (int m = 1; m < 16; m <<= 1)
#pragma unroll
            for (int r = 0; r < 4; ++r)
              rmax[pi][r] = fmaxf(rmax[pi][r], __shfl_xor(rmax[pi][r], m, 64));
          if (col == 0) {
#pragma unroll
            for (int r = 0; r < 4; ++r) {
              int lrow = qd * 4 + r;     // C row = quad*4+reg (m89/R4-verified)
              int row = rbase + lrow;
              if (row < TT)
                out[(row * BBATCH + b) * OC + 20 + dir * PP + p] =
                    rmax[pi][r] * N1W[lrow][p];
            }
          }
        }
      }
    }
    __syncthreads();  // CROW + ARGJ visible block-wide

    // ---- Phase D: mean-att accumulation ----
    if (active) {
      for (int jb = 0; jb < TT; jb += 4) {
        v4f cr[4];
#pragma unroll
        for (int r = 0; r < 4; ++r) cr[r] = *(const v4f*)&CROW[sl + r][jb];
#pragma unroll
        for (int q = 0; q < 4; ++q) {
          int j = jb + q;
          float s2a = S2V[c0i][j][k0];
          float s2b = S2V[c1i][j][k1];
#pragma unroll
          for (int r = 0; r < 4; ++r) {
            att0[r] = fmaf(cr[r][q], s2a, att0[r]);
            att1[r] = fmaf(cr[r][q], s2b, att1[r]);
          }
        }
      }
    }
    __syncthreads();

    if (active) {
#pragma unroll
      for (int r = 0; r < 4; ++r) {
        float inv = 1.0f / (rs[r] + FEPS);
        CROW[sl + r][lane] = att0[r] * inv;
        if (actd) CROW[sl + r][64 + lane] = att1[r] * inv;
      }
    }
    __syncthreads();

    // ---- Phase E: 120 tasks = 4 rows x {full, mean-att, att2} x 10 p ----
    if (active) {
      for (int tk = lane; tk < 120; tk += 64) {
        int r = tk / 30;
        int q = tk - r * 30;
        int set = q / PP;
        int p = q - set * PP;
        const float* wrow = (set == 0 ? wfull : (set == 1 ? wmean : watt2)) + p * DD;
        // reference quirk: s2.reshape(-1,D)[argmax] == s2f[0, argmax, :] (fwd only)
        const float* gat = s2 + ARGJ[sl + r] * (2 * DD);
        float num = 0.f, nx = 0.f, ny = 0.f;
        for (int c = 0; c < DC; ++c) {
          v4f x4 = *(const v4f*)&S1R[sl + r][4 * c];
          v4f y4;
          if (set == 0)                  y4 = *(const v4f*)&S2V[c][TT - 1][0];
          else if (set == 1 || dir == 1) y4 = *(const v4f*)&CROW[sl + r][4 * c];
          else                           y4 = *(const v4f*)&gat[4 * c];
          v4f w4 = *(const v4f*)&wrow[4 * c];
#pragma unroll
          for (int k = 0; k < 4; ++k) {
            float w2v = w4[k] * w4[k];
            num = fmaf(x4[k] * y4[k], w2v, num);
            nx  = fmaf(x4[k] * x4[k], w2v, nx);
            ny  = fmaf(y4[k] * y4[k], w2v, ny);
          }
        }
        float cres = num * rsqrtf(fmaxf(nx, FEPS)) * rsqrtf(fmaxf(ny, FEPS));
        int ch = (set == 0 ? 0 : (set == 1 ? 40 : 60)) + dir * PP + p;
        out[((i0 + r) * BBATCH + b) * OC + ch] = cres;
      }
    }
    __syncthreads();
  }
}

extern "C" void kernel_launch(void* const* d_in, const int* in_sizes, int n_in,
                              void* d_out, int out_size, void* d_ws, size_t ws_size,
                              hipStream_t stream) {
  const float* s1 = (const float*)d_in[0];
  const float* s2 = (const float*)d_in[1];
  match_fused<<<dim3(512), dim3(256), 0, stream>>>(
      s1, s2,
      (const float*)d_in[2], (const float*)d_in[3],
      (const float*)d_in[4], (const float*)d_in[5],
      (const float*)d_in[6], (const float*)d_in[7],
      (const float*)d_in[8], (const float*)d_in[9],
      (float*)d_out);
}

// Round 7
// 789.892 us; speedup vs baseline: 1.2062x; 1.0807x over previous
//
#include <hip/hip_runtime.h>

#define TT 100
#define DD 100
#define DC 25      // DD/4
#define PP 10
#define BBATCH 256
#define OC 80

typedef float v4f __attribute__((ext_vector_type(4)));
typedef short v8s __attribute__((ext_vector_type(8)));
typedef unsigned v4u __attribute__((ext_vector_type(4)));

static constexpr float FEPS = 1e-6f;
static constexpr float NEG_INF = -3.4e38f;

__device__ __forceinline__ float wsum(float v) {
#pragma unroll
  for (int m = 1; m < 64; m <<= 1) v += __shfl_xor(v, m, 64);
  return v;
}

__device__ __forceinline__ void wargmax(float& v, int& idx) {
#pragma unroll
  for (int m = 1; m < 64; m <<= 1) {
    float ov = __shfl_xor(v, m, 64);
    int   oi = __shfl_xor(idx, m, 64);
    if (ov > v || (ov == v && oi < idx)) { v = ov; idx = oi; }
  }
}

// RNE fp32 pair -> packed bf16x2. PURE INTEGER ALU — no structs/unions:
// aggregate copies through __hip_bfloat162/union were demoted to scratch
// (R5/R6: ~1 GB/dispatch HBM scratch traffic).
__device__ __forceinline__ unsigned pkbf(float lo, float hi) {
  unsigned a = __float_as_uint(lo);
  unsigned b = __float_as_uint(hi);
  a += 0x7FFFu + ((a >> 16) & 1u);
  b += 0x7FFFu + ((b >> 16) & 1u);
  return (a >> 16) | (b & 0xFFFF0000u);
}

// A-operand frag: 8 bf16 of s1row[d]*w^2[d] at d = kc*32 + qd*8 (zero-padded K=128)
__device__ __forceinline__ v4u afrag(const float* __restrict__ s1row,
                                     const float* __restrict__ wr,
                                     int kc, int qd) {
  const v4f vz = {0.f, 0.f, 0.f, 0.f};
  v4f x0, x1, w0, w1;
  if (kc < 3) {
    int d0 = kc * 32 + qd * 8;
    x0 = *(const v4f*)&s1row[d0];
    x1 = *(const v4f*)&s1row[d0 + 4];
    w0 = *(const v4f*)&wr[d0];
    w1 = *(const v4f*)&wr[d0 + 4];
  } else {                       // d0 = 96 + qd*8: only qd==0 low half valid
    bool ok = (qd == 0);
    x0 = ok ? *(const v4f*)&s1row[96] : vz;
    w0 = ok ? *(const v4f*)&wr[96] : vz;
    x1 = vz; w1 = vz;
  }
  v4u f;
  f.x = pkbf(x0[0] * (w0[0] * w0[0]), x0[1] * (w0[1] * w0[1]));
  f.y = pkbf(x0[2] * (w0[2] * w0[2]), x0[3] * (w0[3] * w0[3]));
  f.z = pkbf(x1[0] * (w1[0] * w1[0]), x1[1] * (w1[1] * w1[1]));
  f.w = pkbf(x1[2] * (w1[2] * w1[2]), x1[3] * (w1[3] * w1[3]));
  return f;
}

__global__ __launch_bounds__(256, 2) void match_fused(
    const float* __restrict__ s1, const float* __restrict__ s2,
    const float* __restrict__ w1, const float* __restrict__ w2,
    const float* __restrict__ w3, const float* __restrict__ w4,
    const float* __restrict__ w5, const float* __restrict__ w6,
    const float* __restrict__ w7, const float* __restrict__ w8,
    float* __restrict__ out)
{
  const int dir  = blockIdx.x & 1;
  const int b    = blockIdx.x >> 1;
  const int doff = dir * DD;
  const int tid  = threadIdx.x;
  const int lane = tid & 63;
  const int wv   = tid >> 6;

  const float* wfull = dir ? w2 : w1;
  const float* wmax  = dir ? w4 : w3;
  const float* wmean = dir ? w6 : w5;
  const float* watt2 = dir ? w8 : w7;   // fwd: max-att (w7); bwd: mean-att (w8)

  // s2 d-chunked: j-stride 16 B (b128 lane-over-j), chunk stride 404 dw (==20 mod 32)
  __shared__ __align__(16) float S2V[DC][TT + 1][4];  // 40.4 KB
  __shared__ __align__(16) float S1R[16][DD];         // 6.4 KB
  __shared__ __align__(16) float CROW[16][DD];        // 6.4 KB
  __shared__ float N2PI[TT];
  __shared__ float N1PI[16];
  __shared__ float N2W[TT][11];   // maxpool 1/norms of s2 (fp32), pad 11
  __shared__ float N1W[16][11];   // maxpool 1/norms of staged s1 rows
  __shared__ int   ARGJ[16];

  // ---- Phase 1: s2 tile ----
  for (int idx = tid; idx < TT * DD; idx += 256) {
    int j = idx / DD, d = idx - j * DD;
    S2V[d >> 2][j][d & 3] = s2[(j * BBATCH + b) * (2 * DD) + doff + d];
  }
  __syncthreads();

  // ---- Phase 2: s2 norms: plain (argmax-exact) + maxpool-weighted ----
  for (int task = tid; task < TT + TT * PP; task += 256) {
    if (task < TT) {
      float a = 0.f;
      for (int c = 0; c < DC; ++c) {
        v4f f = *(const v4f*)&S2V[c][task][0];
#pragma unroll
        for (int k = 0; k < 4; ++k) a = fmaf(f[k], f[k], a);
      }
      N2PI[task] = 1.0f / sqrtf(fmaxf(a, FEPS));
    } else {
      int q = task - TT; int j = q / PP, p = q - j * PP;
      const float* wr = wmax + p * DD;
      float a = 0.f;
      for (int c = 0; c < DC; ++c) {
        v4f f = *(const v4f*)&S2V[c][j][0];
        v4f w = *(const v4f*)&wr[4 * c];
#pragma unroll
        for (int k = 0; k < 4; ++k) a = fmaf(f[k] * f[k], w[k] * w[k], a);
      }
      N2W[j][p] = rsqrtf(fmaxf(a, FEPS));
    }
  }
  __syncthreads();

  const int  j0   = lane;
  const int  j1   = 64 + lane;
  const bool act1 = (j1 < TT);
  const int  j1c  = act1 ? j1 : (TT - 1);
  const bool actd = (64 + lane) < DD;
  const int  d1   = actd ? (64 + lane) : (DD - 1);
  const int  c0i  = lane >> 2, k0 = lane & 3;
  const int  c1i  = d1 >> 2,   k1 = d1 & 3;

  for (int t = 0; t < 7; ++t) {
    const int rbase = t * 16;
    for (int idx = tid; idx < 16 * DD; idx += 256) {
      int r = idx / DD, d = idx - r * DD;
      int row = rbase + r;
      S1R[r][d] = (row < TT) ? s1[(row * BBATCH + b) * (2 * DD) + doff + d] : 0.f;
    }
    __syncthreads();

    // s1 norms (plain + maxpool-weighted), cooperative
    for (int task = tid; task < 16 + 16 * PP; task += 256) {
      if (task < 16) {
        float a = 0.f;
        for (int c = 0; c < DC; ++c) {
          v4f f = *(const v4f*)&S1R[task][4 * c];
#pragma unroll
          for (int k = 0; k < 4; ++k) a = fmaf(f[k], f[k], a);
        }
        N1PI[task] = 1.0f / sqrtf(fmaxf(a, FEPS));
      } else {
        int q = task - 16; int rr = q / PP, p = q - rr * PP;
        const float* wr = wmax + p * DD;
        float a = 0.f;
        for (int c = 0; c < DC; ++c) {
          v4f f = *(const v4f*)&S1R[rr][4 * c];
          v4f w = *(const v4f*)&wr[4 * c];
#pragma unroll
          for (int k = 0; k < 4; ++k) a = fmaf(f[k] * f[k], w[k] * w[k], a);
        }
        N1W[rr][p] = rsqrtf(fmaxf(a, FEPS));
      }
    }
    __syncthreads();

    const int g = t * 4 + wv;
    const int i0 = g * 4;
    const int sl = wv * 4;
    const bool active = (g < 25);

    float rs[4] = {0, 0, 0, 0};
    float att0[4] = {0, 0, 0, 0}, att1[4] = {0, 0, 0, 0};

    // ---- Phase B+C: plain dot (fp32, argmax-exact), cos rows, rowsum, argmax
    if (active) {
      float dot0[4] = {0, 0, 0, 0}, dot1[4] = {0, 0, 0, 0};
      for (int c = 0; c < DC; ++c) {
        v4f s2a4 = *(const v4f*)&S2V[c][j0][0];
        v4f s2b4 = *(const v4f*)&S2V[c][j1c][0];
        v4f s1v[4];
#pragma unroll
        for (int r = 0; r < 4; ++r) s1v[r] = *(const v4f*)&S1R[sl + r][4 * c];
#pragma unroll
        for (int k = 0; k < 4; ++k) {
#pragma unroll
          for (int r = 0; r < 4; ++r) {
            dot0[r] = fmaf(s1v[r][k], s2a4[k], dot0[r]);
            dot1[r] = fmaf(s1v[r][k], s2b4[k], dot1[r]);
          }
        }
      }
#pragma unroll
      for (int r = 0; r < 4; ++r) {
        float n1pi_r = N1PI[sl + r];
        float c0 = dot0[r] * (n1pi_r * N2PI[j0]);
        float c1 = dot1[r] * (n1pi_r * N2PI[j1c]);
        CROW[sl + r][j0] = c0;
        if (act1) CROW[sl + r][j1] = c1;
        rs[r] = wsum(c0 + (act1 ? c1 : 0.f));

        float mv = c0; int mi = j0;
        if (act1 && (c1 > mv)) { mv = c1; mi = j1; }
        wargmax(mv, mi);
        if (lane == 0) ARGJ[sl + r] = mi;
      }
    }

    // ---- MFMA maxpool section (all waves; wave wv: p in {wv, wv+4, wv+8-clamped})
    {
      const int col = lane & 15;
      const int qd  = lane >> 4;

      v4u afr[3][4];
      float rmax[3][4];
#pragma unroll
      for (int pi = 0; pi < 3; ++pi) {
        const int p = (wv + 4 * pi < PP) ? (wv + 4 * pi) : (PP - 1);
        const float* wr = wmax + p * DD;
        const float* s1row = &S1R[col][0];
#pragma unroll
        for (int kc = 0; kc < 4; ++kc) afr[pi][kc] = afrag(s1row, wr, kc, qd);
#pragma unroll
        for (int r = 0; r < 4; ++r) rmax[pi][r] = NEG_INF;
      }

      for (int jt = 0; jt < 7; ++jt) {
        int jr = jt * 16 + col;
        int jc = (jr < TT) ? jr : (TT - 1);
        v4u bfr[4];                       // B = bf16(s2), row = jr
#pragma unroll
        for (int kc = 0; kc < 4; ++kc) {
          const v4f vz = {0.f, 0.f, 0.f, 0.f};
          int ch = kc * 8 + qd * 2;
          v4f y0 = (ch     <= 24) ? *(const v4f*)&S2V[(ch     <= 24) ? ch     : 24][jc][0] : vz;
          v4f y1 = (ch + 1 <= 24) ? *(const v4f*)&S2V[(ch + 1 <= 24) ? ch + 1 : 24][jc][0] : vz;
          v4u f;
          f.x = pkbf(y0[0], y0[1]); f.y = pkbf(y0[2], y0[3]);
          f.z = pkbf(y1[0], y1[1]); f.w = pkbf(y1[2], y1[3]);
          bfr[kc] = f;
        }
#pragma unroll
        for (int pi = 0; pi < 3; ++pi) {
          const int p = (wv + 4 * pi < PP) ? (wv + 4 * pi) : (PP - 1);
          v4f acc = {0.f, 0.f, 0.f, 0.f};
#pragma unroll
          for (int kc = 0; kc < 4; ++kc)
            acc = __builtin_amdgcn_mfma_f32_16x16x32_bf16(
                __builtin_bit_cast(v8s, afr[pi][kc]),
                __builtin_bit_cast(v8s, bfr[kc]), acc, 0, 0, 0);
          if (jr < TT) {                 // C col = lane&15 -> j (m89/R4-verified)
            float n2 = N2W[jr][p];
#pragma unroll
            for (int r = 0; r < 4; ++r)
              rmax[pi][r] = fmaxf(rmax[pi][r], acc[r] * n2);
          }
        }
      }
#pragma unroll
      for (int pi = 0; pi < 3; ++pi) {
        const int p = wv + 4 * pi;
        if (p < PP) {                    // wave-uniform guard
#pragma unroll
          for (int m = 1; m < 16; m <<= 1)
#pragma unroll
            for (int r = 0; r < 4; ++r)
              rmax[pi][r] = fmaxf(rmax[pi][r], __shfl_xor(rmax[pi][r], m, 64));
          if (col == 0) {
#pragma unroll
            for (int r = 0; r < 4; ++r) {
              int lrow = qd * 4 + r;     // C row = quad*4+reg (m89/R4-verified)
              int row = rbase + lrow;
              if (row < TT)
                out[(row * BBATCH + b) * OC + 20 + dir * PP + p] =
                    rmax[pi][r] * N1W[lrow][p];
            }
          }
        }
      }
    }
    __syncthreads();  // CROW + ARGJ visible block-wide

    // ---- Phase D: mean-att accumulation ----
    if (active) {
      for (int jb = 0; jb < TT; jb += 4) {
        v4f cr[4];
#pragma unroll
        for (int r = 0; r < 4; ++r) cr[r] = *(const v4f*)&CROW[sl + r][jb];
#pragma unroll
        for (int q = 0; q < 4; ++q) {
          int j = jb + q;
          float s2a = S2V[c0i][j][k0];
          float s2b = S2V[c1i][j][k1];
#pragma unroll
          for (int r = 0; r < 4; ++r) {
            att0[r] = fmaf(cr[r][q], s2a, att0[r]);
            att1[r] = fmaf(cr[r][q], s2b, att1[r]);
          }
        }
      }
    }
    __syncthreads();

    if (active) {
#pragma unroll
      for (int r = 0; r < 4; ++r) {
        float inv = 1.0f / (rs[r] + FEPS);
        CROW[sl + r][lane] = att0[r] * inv;
        if (actd) CROW[sl + r][64 + lane] = att1[r] * inv;
      }
    }
    __syncthreads();

    // ---- Phase E: 120 tasks = 4 rows x {full, mean-att, att2} x 10 p ----
    if (active) {
      for (int tk = lane; tk < 120; tk += 64) {
        int r = tk / 30;
        int q = tk - r * 30;
        int set = q / PP;
        int p = q - set * PP;
        const float* wrow = (set == 0 ? wfull : (set == 1 ? wmean : watt2)) + p * DD;
        // reference quirk: s2.reshape(-1,D)[argmax] == s2f[0, argmax, :] (fwd only)
        const float* gat = s2 + ARGJ[sl + r] * (2 * DD);
        float num = 0.f, nx = 0.f, ny = 0.f;
        for (int c = 0; c < DC; ++c) {
          v4f x4 = *(const v4f*)&S1R[sl + r][4 * c];
          v4f y4;
          if (set == 0)                  y4 = *(const v4f*)&S2V[c][TT - 1][0];
          else if (set == 1 || dir == 1) y4 = *(const v4f*)&CROW[sl + r][4 * c];
          else                           y4 = *(const v4f*)&gat[4 * c];
          v4f w4 = *(const v4f*)&wrow[4 * c];
#pragma unroll
          for (int k = 0; k < 4; ++k) {
            float w2v = w4[k] * w4[k];
            num = fmaf(x4[k] * y4[k], w2v, num);
            nx  = fmaf(x4[k] * x4[k], w2v, nx);
            ny  = fmaf(y4[k] * y4[k], w2v, ny);
          }
        }
        float cres = num * rsqrtf(fmaxf(nx, FEPS)) * rsqrtf(fmaxf(ny, FEPS));
        int ch = (set == 0 ? 0 : (set == 1 ? 40 : 60)) + dir * PP + p;
        out[((i0 + r) * BBATCH + b) * OC + ch] = cres;
      }
    }
    __syncthreads();
  }
}

extern "C" void kernel_launch(void* const* d_in, const int* in_sizes, int n_in,
                              void* d_out, int out_size, void* d_ws, size_t ws_size,
                              hipStream_t stream) {
  const float* s1 = (const float*)d_in[0];
  const float* s2 = (const float*)d_in[1];
  match_fused<<<dim3(512), dim3(256), 0, stream>>>(
      s1, s2,
      (const float*)d_in[2], (const float*)d_in[3],
      (const float*)d_in[4], (const float*)d_in[5],
      (const float*)d_in[6], (const float*)d_in[7],
      (const float*)d_in[8], (const float*)d_in[9],
      (float*)d_out);
}